// Round 3
// baseline (1162.835 us; speedup 1.0000x reference)
//
#include <hip/hip_runtime.h>
#include <hip/hip_bf16.h>
#include <math.h>

#define B_ 2
#define S_ 2048
#define H_ 2048
#define NH_ 32
#define NKV_ 8
#define D_ 64
#define F_ 3072            // (NH + 2*NKV) * D
#define SCALE_ 0.125f      // 1/sqrt(64)
#define QSCALE_ 0.18033688011112042f   // SCALE_ * log2(e); lets attn use exp2f

using bf16 = __bf16;
using bf16x4 = __attribute__((ext_vector_type(4))) __bf16;
using bf16x8 = __attribute__((ext_vector_type(8))) __bf16;
using f32x4 = __attribute__((ext_vector_type(4))) float;

#define GLOBAL_AS(p) ((__attribute__((address_space(1))) void*)(p))
#define LDS_AS(p)    ((__attribute__((address_space(3))) void*)(p))

// ---------------- fp32 -> bf16 convert (vectorized) ----------------
__global__ void cvt_f32_bf16(const float4* __restrict__ in, bf16* __restrict__ out, int n4) {
    int i = blockIdx.x * 256 + threadIdx.x;
    if (i >= n4) return;
    float4 v = in[i];
    bf16x4 o = {(bf16)v.x, (bf16)v.y, (bf16)v.z, (bf16)v.w};
    *reinterpret_cast<bf16x4*>(out + (size_t)i * 4) = o;
}

// ---------------- transpose + convert: in fp32 [K][N] -> out bf16 [N][K] ----------------
__global__ void transpose_to_bf16(const float* __restrict__ in, bf16* __restrict__ out,
                                  int K, int N) {
    __shared__ float tile[32][33];
    int n0 = blockIdx.x * 32, k0 = blockIdx.y * 32;
    int tx = threadIdx.x, ty = threadIdx.y;   // (32, 8)
#pragma unroll
    for (int i = 0; i < 4; ++i)
        tile[ty + i * 8][tx] = in[(size_t)(k0 + ty + i * 8) * N + n0 + tx];
    __syncthreads();
#pragma unroll
    for (int i = 0; i < 4; ++i)
        out[(size_t)(n0 + ty + i * 8) * K + k0 + tx] = (bf16)tile[tx][ty + i * 8];
}

// ---------------- bf16 MFMA GEMM: C[M][N] = A[M][K] * BT[N][K]^T, fp32 out ----------------
__global__ __launch_bounds__(256) void gemm_bt(const bf16* __restrict__ A,
                                               const bf16* __restrict__ BT,
                                               float* __restrict__ C,
                                               int M, int N, int K) {
    __shared__ __attribute__((aligned(16))) bf16 As[128 * 32];
    __shared__ __attribute__((aligned(16))) bf16 Bs[128 * 32];
    const int tid = threadIdx.x;
    const int w = tid >> 6, lane = tid & 63;
    const int t = lane & 15, quad = lane >> 4;
    const int m0 = blockIdx.y * 128, n0 = blockIdx.x * 128;
    const int wm = (w >> 1) * 64, wn = (w & 1) * 64;
    const int lrow = lane >> 2;
    const int lcol = (lane & 3) * 8;

    f32x4 acc[4][4] = {};

    for (int k0 = 0; k0 < K; k0 += 32) {
#pragma unroll
        for (int i = 0; i < 2; ++i) {
            int c = w * 2 + i;
            const bf16* ga = A + (size_t)(m0 + c * 16 + lrow) * K + k0 + lcol;
            __builtin_amdgcn_global_load_lds(GLOBAL_AS(ga), LDS_AS(As + c * 512), 16, 0, 0);
            const bf16* gb = BT + (size_t)(n0 + c * 16 + lrow) * K + k0 + lcol;
            __builtin_amdgcn_global_load_lds(GLOBAL_AS(gb), LDS_AS(Bs + c * 512), 16, 0, 0);
        }
        __syncthreads();
        bf16x8 a[4], b[4];
#pragma unroll
        for (int i = 0; i < 4; ++i)
            a[i] = *reinterpret_cast<const bf16x8*>(As + (wm + i * 16 + t) * 32 + quad * 8);
#pragma unroll
        for (int j = 0; j < 4; ++j)
            b[j] = *reinterpret_cast<const bf16x8*>(Bs + (wn + j * 16 + t) * 32 + quad * 8);
#pragma unroll
        for (int i = 0; i < 4; ++i)
#pragma unroll
            for (int j = 0; j < 4; ++j)
                acc[i][j] = __builtin_amdgcn_mfma_f32_16x16x32_bf16(a[i], b[j], acc[i][j], 0, 0, 0);
        __syncthreads();
    }
#pragma unroll
    for (int i = 0; i < 4; ++i)
#pragma unroll
        for (int j = 0; j < 4; ++j)
#pragma unroll
            for (int r = 0; r < 4; ++r)
                C[(size_t)(m0 + wm + i * 16 + quad * 4 + r) * N + n0 + wn + j * 16 + t] =
                    acc[i][j][r];
}

// ---------------- RoPE (NeoX) + split; Q pre-scaled by SCALE*log2(e) ----------------
// Q:  [B*NH][S][D]   K: [B*NKV][S][D]   Vt: [B*NKV][D][S]
__global__ void rope_split(const float* __restrict__ qkv, const int* __restrict__ positions,
                           bf16* __restrict__ Q, bf16* __restrict__ Kb, bf16* __restrict__ Vt) {
    int row = blockIdx.x;           // b*S + s
    int head = blockIdx.y;
    int d = threadIdx.x;            // 0..63
    int s = row & (S_ - 1), b = row >> 11;
    const float* base = qkv + (size_t)row * F_;
    if (head < NH_ + NKV_) {
        int isK = head >= NH_;
        int hh = isK ? head - NH_ : head;
        int coloff = isK ? NH_ * D_ + hh * D_ : hh * D_;
        float x = base[coloff + d];
        int i = d & 31;
        float pos = (float)positions[s];
        float inv = __expf(-(float)i * (9.210340371976184f / 32.0f));  // 10000^(-i/32)
        float sn, cs;
        sincosf(pos * inv, &sn, &cs);
        float partner = (d < 32) ? base[coloff + d + 32] : base[coloff + d - 32];
        float sign = (d < 32) ? -1.0f : 1.0f;
        float o = x * cs + sign * partner * sn;
        if (!isK)
            Q[((size_t)(b * NH_ + hh) * S_ + s) * D_ + d] = (bf16)(o * QSCALE_);
        else
            Kb[((size_t)(b * NKV_ + hh) * S_ + s) * D_ + d] = (bf16)o;
    } else {
        int hv = head - NH_ - NKV_;
        float v = base[NH_ * D_ + NKV_ * D_ + hv * D_ + d];
        Vt[((size_t)(b * NKV_ + hv) * D_ + d) * S_ + s] = (bf16)v;
    }
}

// ---------------- causal GQA flash attention, S^T formulation + 2-way key split ----------------
// Block = 2 waves. Each block handles the balanced tile pair (i, 127-i); within a
// tile, wave w does 64-key chunks c = w, w+2, ... with private online-softmax
// state; states merge through LDS at tile end. 8192 waves -> 8 waves/SIMD.
__global__ __launch_bounds__(128, 8) void flash_attn(const bf16* __restrict__ Q,
                                                     const bf16* __restrict__ Kb,
                                                     const bf16* __restrict__ Vt,
                                                     bf16* __restrict__ ctx) {
    __shared__ __attribute__((aligned(16))) bf16 Plds[2][16 * 72];  // per-wave P buffer
    __shared__ __attribute__((aligned(16))) float Olds[4][64 * 4];  // wave1 O for merge
    __shared__ float Mlds[16], Llds[16];
    const int tid = threadIdx.x;
    const int w = tid >> 6, lane = tid & 63;
    const int t = lane & 15, quad = lane >> 4;
    const int h = blockIdx.y, b = blockIdx.z;
    const int bh = b * NH_ + h;
    const int bhk = b * NKV_ + (h >> 2);
    const bf16* Kbase = Kb + (size_t)bhk * S_ * D_;
    const bf16* Vbase = Vt + (size_t)bhk * D_ * S_;

#pragma unroll
    for (int rep = 0; rep < 2; ++rep) {
        const int tileIdx = rep ? (127 - (int)blockIdx.x) : (int)blockIdx.x;
        const int qbase = tileIdx * 16;
        const int kend = qbase + 16;

        const bf16* Qp = Q + ((size_t)bh * S_ + qbase) * D_;
        bf16x8 qf0 = *reinterpret_cast<const bf16x8*>(Qp + t * D_ + quad * 8);
        bf16x8 qf1 = *reinterpret_cast<const bf16x8*>(Qp + t * D_ + 32 + quad * 8);

        f32x4 o[4] = {};
        float m = -1e30f, l = 0.f;

        bf16x8 kf[4][2];
        {
            const int k0 = w * 64;
#pragma unroll
            for (int tl = 0; tl < 4; ++tl)
#pragma unroll
                for (int hf = 0; hf < 2; ++hf)
                    kf[tl][hf] = *reinterpret_cast<const bf16x8*>(
                        Kbase + (size_t)(k0 + tl * 16 + t) * D_ + hf * 32 + quad * 8);
        }

        for (int k0 = w * 64; k0 < kend; k0 += 128) {
            // V frags for current chunk (independent of softmax; issue early)
            bf16x8 vf[4][2];
#pragma unroll
            for (int dt = 0; dt < 4; ++dt)
#pragma unroll
                for (int hf = 0; hf < 2; ++hf)
                    vf[dt][hf] = *reinterpret_cast<const bf16x8*>(
                        Vbase + (size_t)(dt * 16 + t) * S_ + k0 + hf * 32 + quad * 8);

            f32x4 sa[4] = {};
#pragma unroll
            for (int tl = 0; tl < 4; ++tl) {
                sa[tl] = __builtin_amdgcn_mfma_f32_16x16x32_bf16(kf[tl][0], qf0, sa[tl], 0, 0, 0);
                sa[tl] = __builtin_amdgcn_mfma_f32_16x16x32_bf16(kf[tl][1], qf1, sa[tl], 0, 0, 0);
            }
            // prefetch this wave's next chunk (+128 keys)
            if (k0 + 128 < kend) {
                const int kn = k0 + 128;
#pragma unroll
                for (int tl = 0; tl < 4; ++tl)
#pragma unroll
                    for (int hf = 0; hf < 2; ++hf)
                        kf[tl][hf] = *reinterpret_cast<const bf16x8*>(
                            Kbase + (size_t)(kn + tl * 16 + t) * D_ + hf * 32 + quad * 8);
            }
            // causal mask: only the tile's last chunk touches the diagonal
            if (k0 + 64 >= kend) {
                const int qrow = qbase + t;
#pragma unroll
                for (int tl = 0; tl < 4; ++tl)
#pragma unroll
                    for (int r = 0; r < 4; ++r)
                        if (k0 + tl * 16 + quad * 4 + r > qrow) sa[tl][r] = -1e30f;
            }
            // online softmax over 64 keys; row = q = t (scores are base-2 scaled)
            float mx = -1e30f;
#pragma unroll
            for (int tl = 0; tl < 4; ++tl)
#pragma unroll
                for (int r = 0; r < 4; ++r) mx = fmaxf(mx, sa[tl][r]);
            mx = fmaxf(mx, __shfl_xor(mx, 16, 64));
            mx = fmaxf(mx, __shfl_xor(mx, 32, 64));
            const float mn = fmaxf(m, mx);
            const float alpha = exp2f(m - mn);
            m = mn;
            float rs = 0.f;
#pragma unroll
            for (int tl = 0; tl < 4; ++tl) {
                float p0 = exp2f(sa[tl][0] - mn);
                float p1 = exp2f(sa[tl][1] - mn);
                float p2 = exp2f(sa[tl][2] - mn);
                float p3 = exp2f(sa[tl][3] - mn);
                rs += (p0 + p1) + (p2 + p3);
                bf16x4 pk = {(bf16)p0, (bf16)p1, (bf16)p2, (bf16)p3};
                *reinterpret_cast<bf16x4*>(&Plds[w][t * 72 + tl * 16 + quad * 4]) = pk;
            }
#pragma unroll
            for (int dt = 0; dt < 4; ++dt)
#pragma unroll
                for (int r = 0; r < 4; ++r) o[dt][r] *= alpha;
            rs += __shfl_xor(rs, 16, 64);
            rs += __shfl_xor(rs, 32, 64);
            l = l * alpha + rs;

            asm volatile("s_waitcnt lgkmcnt(0)" ::: "memory");
            bf16x8 pf0 = *reinterpret_cast<const bf16x8*>(&Plds[w][t * 72 + quad * 8]);
            bf16x8 pf1 = *reinterpret_cast<const bf16x8*>(&Plds[w][t * 72 + 32 + quad * 8]);
#pragma unroll
            for (int dt = 0; dt < 4; ++dt) {
                o[dt] = __builtin_amdgcn_mfma_f32_16x16x32_bf16(vf[dt][0], pf0, o[dt], 0, 0, 0);
                o[dt] = __builtin_amdgcn_mfma_f32_16x16x32_bf16(vf[dt][1], pf1, o[dt], 0, 0, 0);
            }
        }

        // ---- merge the two waves' partial states ----
        __syncthreads();
        if (w == 1) {
#pragma unroll
            for (int dt = 0; dt < 4; ++dt)
                *reinterpret_cast<f32x4*>(&Olds[dt][lane * 4]) = o[dt];
            if (quad == 0) { Mlds[t] = m; Llds[t] = l; }
        }
        __syncthreads();
        if (w == 0) {
            const float m1 = Mlds[t], l1 = Llds[t];
            const float mn = fmaxf(m, m1);
            const float a0 = exp2f(m - mn), a1 = exp2f(m1 - mn);
            const float inv = 1.0f / (l * a0 + l1 * a1);
            const size_t row = (size_t)b * S_ + qbase + t;
#pragma unroll
            for (int dt = 0; dt < 4; ++dt) {
                f32x4 o1 = *reinterpret_cast<const f32x4*>(&Olds[dt][lane * 4]);
                bf16x4 ov = {(bf16)((o[dt][0] * a0 + o1[0] * a1) * inv),
                             (bf16)((o[dt][1] * a0 + o1[1] * a1) * inv),
                             (bf16)((o[dt][2] * a0 + o1[2] * a1) * inv),
                             (bf16)((o[dt][3] * a0 + o1[3] * a1) * inv)};
                *reinterpret_cast<bf16x4*>(ctx + row * (NH_ * D_) + h * D_ + dt * 16 + quad * 4) =
                    ov;
            }
        }
    }
}

extern "C" void kernel_launch(void* const* d_in, const int* in_sizes, int n_in,
                              void* d_out, int out_size, void* d_ws, size_t ws_size,
                              hipStream_t stream) {
    const int* positions = (const int*)d_in[0];
    const float* hidden = (const float*)d_in[1];
    const float* Wqkv = (const float*)d_in[2];
    const float* Wo = (const float*)d_in[3];
    float* out = (float*)d_out;

    char* ws = (char*)d_ws;
    size_t off = 0;
    auto carve = [&](size_t bytes) {
        void* p = ws + off;
        off += (bytes + 255) & ~(size_t)255;
        return p;
    };
    bf16* hidB = (bf16*)carve((size_t)B_ * S_ * H_ * 2);
    bf16* WqkvT = (bf16*)carve((size_t)F_ * H_ * 2);
    bf16* WoT = (bf16*)carve((size_t)H_ * H_ * 2);
    float* qkv = (float*)carve((size_t)B_ * S_ * F_ * 4);
    bf16* Qb = (bf16*)carve((size_t)B_ * NH_ * S_ * D_ * 2);
    bf16* Kbb = (bf16*)carve((size_t)B_ * NKV_ * S_ * D_ * 2);
    bf16* Vt = (bf16*)carve((size_t)B_ * NKV_ * S_ * D_ * 2);
    bf16* ctx = (bf16*)carve((size_t)B_ * S_ * NH_ * D_ * 2);

    cvt_f32_bf16<<<(B_ * S_ * H_ / 4 + 255) / 256, 256, 0, stream>>>((const float4*)hidden, hidB,
                                                                     B_ * S_ * H_ / 4);
    transpose_to_bf16<<<dim3(F_ / 32, H_ / 32), dim3(32, 8), 0, stream>>>(Wqkv, WqkvT, H_, F_);
    transpose_to_bf16<<<dim3(H_ / 32, H_ / 32), dim3(32, 8), 0, stream>>>(Wo, WoT, H_, H_);
    gemm_bt<<<dim3(F_ / 128, (B_ * S_) / 128), 256, 0, stream>>>(hidB, WqkvT, qkv, B_ * S_, F_, H_);
    rope_split<<<dim3(B_ * S_, NH_ + 2 * NKV_), 64, 0, stream>>>(qkv, positions, Qb, Kbb, Vt);
    flash_attn<<<dim3(64, NH_, B_), 128, 0, stream>>>(Qb, Kbb, Vt, ctx);
    gemm_bt<<<dim3(H_ / 128, (B_ * S_) / 128), 256, 0, stream>>>(ctx, WoT, out, B_ * S_, H_, H_);
}

// Round 4
// 966.338 us; speedup vs baseline: 1.2033x; 1.2033x over previous
//
#include <hip/hip_runtime.h>
#include <hip/hip_bf16.h>
#include <math.h>

#define B_ 2
#define S_ 2048
#define H_ 2048
#define NH_ 32
#define NKV_ 8
#define D_ 64
#define F_ 3072            // (NH + 2*NKV) * D
#define SCALE_ 0.125f      // 1/sqrt(64)
#define QSCALE_ 0.18033688011112042f   // SCALE_ * log2(e); lets attn use exp2f

using bf16 = __bf16;
using bf16x4 = __attribute__((ext_vector_type(4))) __bf16;
using bf16x8 = __attribute__((ext_vector_type(8))) __bf16;
using f32x4 = __attribute__((ext_vector_type(4))) float;

#define GLOBAL_AS(p) ((__attribute__((address_space(1))) void*)(p))
#define LDS_AS(p)    ((__attribute__((address_space(3))) void*)(p))

// ---------------- fp32 -> bf16 convert (vectorized) ----------------
__global__ void cvt_f32_bf16(const float4* __restrict__ in, bf16* __restrict__ out, int n4) {
    int i = blockIdx.x * 256 + threadIdx.x;
    if (i >= n4) return;
    float4 v = in[i];
    bf16x4 o = {(bf16)v.x, (bf16)v.y, (bf16)v.z, (bf16)v.w};
    *reinterpret_cast<bf16x4*>(out + (size_t)i * 4) = o;
}

// ---------------- transpose + convert: in fp32 [K][N] -> out bf16 [N][K] ----------------
__global__ void transpose_to_bf16(const float* __restrict__ in, bf16* __restrict__ out,
                                  int K, int N) {
    __shared__ float tile[32][33];
    int n0 = blockIdx.x * 32, k0 = blockIdx.y * 32;
    int tx = threadIdx.x, ty = threadIdx.y;   // (32, 8)
#pragma unroll
    for (int i = 0; i < 4; ++i)
        tile[ty + i * 8][tx] = in[(size_t)(k0 + ty + i * 8) * N + n0 + tx];
    __syncthreads();
#pragma unroll
    for (int i = 0; i < 4; ++i)
        out[(size_t)(n0 + ty + i * 8) * K + k0 + tx] = (bf16)tile[tx][ty + i * 8];
}

// ---------------- bf16 MFMA GEMM: C[M][N] = A[M][K] * BT[N][K]^T, fp32 out ----------------
__global__ __launch_bounds__(256) void gemm_bt(const bf16* __restrict__ A,
                                               const bf16* __restrict__ BT,
                                               float* __restrict__ C,
                                               int M, int N, int K) {
    __shared__ __attribute__((aligned(16))) bf16 As[128 * 32];
    __shared__ __attribute__((aligned(16))) bf16 Bs[128 * 32];
    const int tid = threadIdx.x;
    const int w = tid >> 6, lane = tid & 63;
    const int t = lane & 15, quad = lane >> 4;
    const int m0 = blockIdx.y * 128, n0 = blockIdx.x * 128;
    const int wm = (w >> 1) * 64, wn = (w & 1) * 64;
    const int lrow = lane >> 2;
    const int lcol = (lane & 3) * 8;

    f32x4 acc[4][4] = {};

    for (int k0 = 0; k0 < K; k0 += 32) {
#pragma unroll
        for (int i = 0; i < 2; ++i) {
            int c = w * 2 + i;
            const bf16* ga = A + (size_t)(m0 + c * 16 + lrow) * K + k0 + lcol;
            __builtin_amdgcn_global_load_lds(GLOBAL_AS(ga), LDS_AS(As + c * 512), 16, 0, 0);
            const bf16* gb = BT + (size_t)(n0 + c * 16 + lrow) * K + k0 + lcol;
            __builtin_amdgcn_global_load_lds(GLOBAL_AS(gb), LDS_AS(Bs + c * 512), 16, 0, 0);
        }
        __syncthreads();
        bf16x8 a[4], b[4];
#pragma unroll
        for (int i = 0; i < 4; ++i)
            a[i] = *reinterpret_cast<const bf16x8*>(As + (wm + i * 16 + t) * 32 + quad * 8);
#pragma unroll
        for (int j = 0; j < 4; ++j)
            b[j] = *reinterpret_cast<const bf16x8*>(Bs + (wn + j * 16 + t) * 32 + quad * 8);
#pragma unroll
        for (int i = 0; i < 4; ++i)
#pragma unroll
            for (int j = 0; j < 4; ++j)
                acc[i][j] = __builtin_amdgcn_mfma_f32_16x16x32_bf16(a[i], b[j], acc[i][j], 0, 0, 0);
        __syncthreads();
    }
#pragma unroll
    for (int i = 0; i < 4; ++i)
#pragma unroll
        for (int j = 0; j < 4; ++j)
#pragma unroll
            for (int r = 0; r < 4; ++r)
                C[(size_t)(m0 + wm + i * 16 + quad * 4 + r) * N + n0 + wn + j * 16 + t] =
                    acc[i][j][r];
}

// ---------------- RoPE (NeoX) + split; Q pre-scaled by SCALE*log2(e) ----------------
// Q:  [B*NH][S][D]   K: [B*NKV][S][D]   Vt: [B*NKV][D][S]
__global__ void rope_split(const float* __restrict__ qkv, const int* __restrict__ positions,
                           bf16* __restrict__ Q, bf16* __restrict__ Kb, bf16* __restrict__ Vt) {
    int row = blockIdx.x;           // b*S + s
    int head = blockIdx.y;
    int d = threadIdx.x;            // 0..63
    int s = row & (S_ - 1), b = row >> 11;
    const float* base = qkv + (size_t)row * F_;
    if (head < NH_ + NKV_) {
        int isK = head >= NH_;
        int hh = isK ? head - NH_ : head;
        int coloff = isK ? NH_ * D_ + hh * D_ : hh * D_;
        float x = base[coloff + d];
        int i = d & 31;
        float pos = (float)positions[s];
        float inv = __expf(-(float)i * (9.210340371976184f / 32.0f));  // 10000^(-i/32)
        float sn, cs;
        sincosf(pos * inv, &sn, &cs);
        float partner = (d < 32) ? base[coloff + d + 32] : base[coloff + d - 32];
        float sign = (d < 32) ? -1.0f : 1.0f;
        float o = x * cs + sign * partner * sn;
        if (!isK)
            Q[((size_t)(b * NH_ + hh) * S_ + s) * D_ + d] = (bf16)(o * QSCALE_);
        else
            Kb[((size_t)(b * NKV_ + hh) * S_ + s) * D_ + d] = (bf16)o;
    } else {
        int hv = head - NH_ - NKV_;
        float v = base[NH_ * D_ + NKV_ * D_ + hv * D_ + d];
        Vt[((size_t)(b * NKV_ + hv) * D_ + d) * S_ + s] = (bf16)v;
    }
}

// ---------------- causal GQA flash attention, S^T formulation + 2-way key split ----------------
// Block = 2 waves. Each block handles the balanced tile pair (i, 127-i); within a
// tile, wave w does 64-key chunks c = w, w+2, ... with private online-softmax
// state; states merge through LDS at tile end. 8192 waves total.
// launch_bounds(128, 6): 85-VGPR cap — peak live state is ~80 regs; the (128,8)
// 64-reg cap caused catastrophic scratch spill (R3: 4 GB HBM traffic/dispatch).
__global__ __launch_bounds__(128, 6) void flash_attn(const bf16* __restrict__ Q,
                                                     const bf16* __restrict__ Kb,
                                                     const bf16* __restrict__ Vt,
                                                     bf16* __restrict__ ctx) {
    __shared__ __attribute__((aligned(16))) bf16 Plds[2][16 * 72];  // per-wave P buffer
    __shared__ __attribute__((aligned(16))) float Olds[4][64 * 4];  // wave1 O for merge
    __shared__ float Mlds[16], Llds[16];
    const int tid = threadIdx.x;
    const int w = tid >> 6, lane = tid & 63;
    const int t = lane & 15, quad = lane >> 4;
    const int h = blockIdx.y, b = blockIdx.z;
    const int bh = b * NH_ + h;
    const int bhk = b * NKV_ + (h >> 2);
    const bf16* Kbase = Kb + (size_t)bhk * S_ * D_;
    const bf16* Vbase = Vt + (size_t)bhk * D_ * S_;

#pragma unroll
    for (int rep = 0; rep < 2; ++rep) {
        const int tileIdx = rep ? (127 - (int)blockIdx.x) : (int)blockIdx.x;
        const int qbase = tileIdx * 16;
        const int kend = qbase + 16;

        const bf16* Qp = Q + ((size_t)bh * S_ + qbase) * D_;
        bf16x8 qf0 = *reinterpret_cast<const bf16x8*>(Qp + t * D_ + quad * 8);
        bf16x8 qf1 = *reinterpret_cast<const bf16x8*>(Qp + t * D_ + 32 + quad * 8);

        f32x4 o[4] = {};
        float m = -1e30f, l = 0.f;

        bf16x8 kf[4][2];
        {
            const int k0 = w * 64;
#pragma unroll
            for (int tl = 0; tl < 4; ++tl)
#pragma unroll
                for (int hf = 0; hf < 2; ++hf)
                    kf[tl][hf] = *reinterpret_cast<const bf16x8*>(
                        Kbase + (size_t)(k0 + tl * 16 + t) * D_ + hf * 32 + quad * 8);
        }

        for (int k0 = w * 64; k0 < kend; k0 += 128) {
            // V frags for current chunk (independent of softmax; issue early)
            bf16x8 vf[4][2];
#pragma unroll
            for (int dt = 0; dt < 4; ++dt)
#pragma unroll
                for (int hf = 0; hf < 2; ++hf)
                    vf[dt][hf] = *reinterpret_cast<const bf16x8*>(
                        Vbase + (size_t)(dt * 16 + t) * S_ + k0 + hf * 32 + quad * 8);

            f32x4 sa[4] = {};
#pragma unroll
            for (int tl = 0; tl < 4; ++tl) {
                sa[tl] = __builtin_amdgcn_mfma_f32_16x16x32_bf16(kf[tl][0], qf0, sa[tl], 0, 0, 0);
                sa[tl] = __builtin_amdgcn_mfma_f32_16x16x32_bf16(kf[tl][1], qf1, sa[tl], 0, 0, 0);
            }
            // prefetch this wave's next chunk (+128 keys)
            if (k0 + 128 < kend) {
                const int kn = k0 + 128;
#pragma unroll
                for (int tl = 0; tl < 4; ++tl)
#pragma unroll
                    for (int hf = 0; hf < 2; ++hf)
                        kf[tl][hf] = *reinterpret_cast<const bf16x8*>(
                            Kbase + (size_t)(kn + tl * 16 + t) * D_ + hf * 32 + quad * 8);
            }
            // causal mask: only the tile's last chunk touches the diagonal
            if (k0 + 64 >= kend) {
                const int qrow = qbase + t;
#pragma unroll
                for (int tl = 0; tl < 4; ++tl)
#pragma unroll
                    for (int r = 0; r < 4; ++r)
                        if (k0 + tl * 16 + quad * 4 + r > qrow) sa[tl][r] = -1e30f;
            }
            // online softmax over 64 keys; row = q = t (scores are base-2 scaled)
            float mx = -1e30f;
#pragma unroll
            for (int tl = 0; tl < 4; ++tl)
#pragma unroll
                for (int r = 0; r < 4; ++r) mx = fmaxf(mx, sa[tl][r]);
            mx = fmaxf(mx, __shfl_xor(mx, 16, 64));
            mx = fmaxf(mx, __shfl_xor(mx, 32, 64));
            const float mn = fmaxf(m, mx);
            const float alpha = exp2f(m - mn);
            m = mn;
            float rs = 0.f;
#pragma unroll
            for (int tl = 0; tl < 4; ++tl) {
                float p0 = exp2f(sa[tl][0] - mn);
                float p1 = exp2f(sa[tl][1] - mn);
                float p2 = exp2f(sa[tl][2] - mn);
                float p3 = exp2f(sa[tl][3] - mn);
                rs += (p0 + p1) + (p2 + p3);
                bf16x4 pk = {(bf16)p0, (bf16)p1, (bf16)p2, (bf16)p3};
                *reinterpret_cast<bf16x4*>(&Plds[w][t * 72 + tl * 16 + quad * 4]) = pk;
            }
#pragma unroll
            for (int dt = 0; dt < 4; ++dt)
#pragma unroll
                for (int r = 0; r < 4; ++r) o[dt][r] *= alpha;
            rs += __shfl_xor(rs, 16, 64);
            rs += __shfl_xor(rs, 32, 64);
            l = l * alpha + rs;

            asm volatile("s_waitcnt lgkmcnt(0)" ::: "memory");
            bf16x8 pf0 = *reinterpret_cast<const bf16x8*>(&Plds[w][t * 72 + quad * 8]);
            bf16x8 pf1 = *reinterpret_cast<const bf16x8*>(&Plds[w][t * 72 + 32 + quad * 8]);
#pragma unroll
            for (int dt = 0; dt < 4; ++dt) {
                o[dt] = __builtin_amdgcn_mfma_f32_16x16x32_bf16(vf[dt][0], pf0, o[dt], 0, 0, 0);
                o[dt] = __builtin_amdgcn_mfma_f32_16x16x32_bf16(vf[dt][1], pf1, o[dt], 0, 0, 0);
            }
        }

        // ---- merge the two waves' partial states ----
        __syncthreads();
        if (w == 1) {
#pragma unroll
            for (int dt = 0; dt < 4; ++dt)
                *reinterpret_cast<f32x4*>(&Olds[dt][lane * 4]) = o[dt];
            if (quad == 0) { Mlds[t] = m; Llds[t] = l; }
        }
        __syncthreads();
        if (w == 0) {
            const float m1 = Mlds[t], l1 = Llds[t];
            const float mn = fmaxf(m, m1);
            const float a0 = exp2f(m - mn), a1 = exp2f(m1 - mn);
            const float inv = 1.0f / (l * a0 + l1 * a1);
            const size_t row = (size_t)b * S_ + qbase + t;
#pragma unroll
            for (int dt = 0; dt < 4; ++dt) {
                f32x4 o1 = *reinterpret_cast<const f32x4*>(&Olds[dt][lane * 4]);
                bf16x4 ov = {(bf16)((o[dt][0] * a0 + o1[0] * a1) * inv),
                             (bf16)((o[dt][1] * a0 + o1[1] * a1) * inv),
                             (bf16)((o[dt][2] * a0 + o1[2] * a1) * inv),
                             (bf16)((o[dt][3] * a0 + o1[3] * a1) * inv)};
                *reinterpret_cast<bf16x4*>(ctx + row * (NH_ * D_) + h * D_ + dt * 16 + quad * 4) =
                    ov;
            }
        }
    }
}

extern "C" void kernel_launch(void* const* d_in, const int* in_sizes, int n_in,
                              void* d_out, int out_size, void* d_ws, size_t ws_size,
                              hipStream_t stream) {
    const int* positions = (const int*)d_in[0];
    const float* hidden = (const float*)d_in[1];
    const float* Wqkv = (const float*)d_in[2];
    const float* Wo = (const float*)d_in[3];
    float* out = (float*)d_out;

    char* ws = (char*)d_ws;
    size_t off = 0;
    auto carve = [&](size_t bytes) {
        void* p = ws + off;
        off += (bytes + 255) & ~(size_t)255;
        return p;
    };
    bf16* hidB = (bf16*)carve((size_t)B_ * S_ * H_ * 2);
    bf16* WqkvT = (bf16*)carve((size_t)F_ * H_ * 2);
    bf16* WoT = (bf16*)carve((size_t)H_ * H_ * 2);
    float* qkv = (float*)carve((size_t)B_ * S_ * F_ * 4);
    bf16* Qb = (bf16*)carve((size_t)B_ * NH_ * S_ * D_ * 2);
    bf16* Kbb = (bf16*)carve((size_t)B_ * NKV_ * S_ * D_ * 2);
    bf16* Vt = (bf16*)carve((size_t)B_ * NKV_ * S_ * D_ * 2);
    bf16* ctx = (bf16*)carve((size_t)B_ * S_ * NH_ * D_ * 2);

    cvt_f32_bf16<<<(B_ * S_ * H_ / 4 + 255) / 256, 256, 0, stream>>>((const float4*)hidden, hidB,
                                                                     B_ * S_ * H_ / 4);
    transpose_to_bf16<<<dim3(F_ / 32, H_ / 32), dim3(32, 8), 0, stream>>>(Wqkv, WqkvT, H_, F_);
    transpose_to_bf16<<<dim3(H_ / 32, H_ / 32), dim3(32, 8), 0, stream>>>(Wo, WoT, H_, H_);
    gemm_bt<<<dim3(F_ / 128, (B_ * S_) / 128), 256, 0, stream>>>(hidB, WqkvT, qkv, B_ * S_, F_, H_);
    rope_split<<<dim3(B_ * S_, NH_ + 2 * NKV_), 64, 0, stream>>>(qkv, positions, Qb, Kbb, Vt);
    flash_attn<<<dim3(64, NH_, B_), 128, 0, stream>>>(Qb, Kbb, Vt, ctx);
    gemm_bt<<<dim3(H_ / 128, (B_ * S_) / 128), 256, 0, stream>>>(ctx, WoT, out, B_ * S_, H_, H_);
}

// Round 5
// 388.297 us; speedup vs baseline: 2.9947x; 2.4887x over previous
//
#include <hip/hip_runtime.h>
#include <hip/hip_bf16.h>
#include <math.h>

#define B_ 2
#define S_ 2048
#define H_ 2048
#define NH_ 32
#define NKV_ 8
#define D_ 64
#define F_ 3072            // (NH + 2*NKV) * D
#define SCALE_ 0.125f      // 1/sqrt(64)
#define QSCALE_ 0.18033688011112042f   // SCALE_ * log2(e); lets attn use exp2f

using bf16 = __bf16;
using bf16x4 = __attribute__((ext_vector_type(4))) __bf16;
using bf16x8 = __attribute__((ext_vector_type(8))) __bf16;
using f32x4 = __attribute__((ext_vector_type(4))) float;

#define GLOBAL_AS(p) ((__attribute__((address_space(1))) void*)(p))
#define LDS_AS(p)    ((__attribute__((address_space(3))) void*)(p))

// ---------------- fp32 -> bf16 convert (vectorized) ----------------
__global__ void cvt_f32_bf16(const float4* __restrict__ in, bf16* __restrict__ out, int n4) {
    int i = blockIdx.x * 256 + threadIdx.x;
    if (i >= n4) return;
    float4 v = in[i];
    bf16x4 o = {(bf16)v.x, (bf16)v.y, (bf16)v.z, (bf16)v.w};
    *reinterpret_cast<bf16x4*>(out + (size_t)i * 4) = o;
}

// ---------------- transpose + convert: in fp32 [K][N] -> out bf16 [N][K] ----------------
__global__ void transpose_to_bf16(const float* __restrict__ in, bf16* __restrict__ out,
                                  int K, int N) {
    __shared__ float tile[32][33];
    int n0 = blockIdx.x * 32, k0 = blockIdx.y * 32;
    int tx = threadIdx.x, ty = threadIdx.y;   // (32, 8)
#pragma unroll
    for (int i = 0; i < 4; ++i)
        tile[ty + i * 8][tx] = in[(size_t)(k0 + ty + i * 8) * N + n0 + tx];
    __syncthreads();
#pragma unroll
    for (int i = 0; i < 4; ++i)
        out[(size_t)(n0 + ty + i * 8) * K + k0 + tx] = (bf16)tile[tx][ty + i * 8];
}

// ---------------- bf16 MFMA GEMM: C[M][N] = A[M][K] * BT[N][K]^T, fp32 out ----------------
__global__ __launch_bounds__(256) void gemm_bt(const bf16* __restrict__ A,
                                               const bf16* __restrict__ BT,
                                               float* __restrict__ C,
                                               int M, int N, int K) {
    __shared__ __attribute__((aligned(16))) bf16 As[128 * 32];
    __shared__ __attribute__((aligned(16))) bf16 Bs[128 * 32];
    const int tid = threadIdx.x;
    const int w = tid >> 6, lane = tid & 63;
    const int t = lane & 15, quad = lane >> 4;
    const int m0 = blockIdx.y * 128, n0 = blockIdx.x * 128;
    const int wm = (w >> 1) * 64, wn = (w & 1) * 64;
    const int lrow = lane >> 2;
    const int lcol = (lane & 3) * 8;

    f32x4 acc[4][4] = {};

    for (int k0 = 0; k0 < K; k0 += 32) {
#pragma unroll
        for (int i = 0; i < 2; ++i) {
            int c = w * 2 + i;
            const bf16* ga = A + (size_t)(m0 + c * 16 + lrow) * K + k0 + lcol;
            __builtin_amdgcn_global_load_lds(GLOBAL_AS(ga), LDS_AS(As + c * 512), 16, 0, 0);
            const bf16* gb = BT + (size_t)(n0 + c * 16 + lrow) * K + k0 + lcol;
            __builtin_amdgcn_global_load_lds(GLOBAL_AS(gb), LDS_AS(Bs + c * 512), 16, 0, 0);
        }
        __syncthreads();
        bf16x8 a[4], b[4];
#pragma unroll
        for (int i = 0; i < 4; ++i)
            a[i] = *reinterpret_cast<const bf16x8*>(As + (wm + i * 16 + t) * 32 + quad * 8);
#pragma unroll
        for (int j = 0; j < 4; ++j)
            b[j] = *reinterpret_cast<const bf16x8*>(Bs + (wn + j * 16 + t) * 32 + quad * 8);
#pragma unroll
        for (int i = 0; i < 4; ++i)
#pragma unroll
            for (int j = 0; j < 4; ++j)
                acc[i][j] = __builtin_amdgcn_mfma_f32_16x16x32_bf16(a[i], b[j], acc[i][j], 0, 0, 0);
        __syncthreads();
    }
#pragma unroll
    for (int i = 0; i < 4; ++i)
#pragma unroll
        for (int j = 0; j < 4; ++j)
#pragma unroll
            for (int r = 0; r < 4; ++r)
                C[(size_t)(m0 + wm + i * 16 + quad * 4 + r) * N + n0 + wn + j * 16 + t] =
                    acc[i][j][r];
}

// ---------------- RoPE (NeoX) + split; Q pre-scaled by SCALE*log2(e) ----------------
// Q:  [B*NH][S][D]   K: [B*NKV][S][D]   Vt: [B*NKV][D][S]
__global__ void rope_split(const float* __restrict__ qkv, const int* __restrict__ positions,
                           bf16* __restrict__ Q, bf16* __restrict__ Kb, bf16* __restrict__ Vt) {
    int row = blockIdx.x;           // b*S + s
    int head = blockIdx.y;
    int d = threadIdx.x;            // 0..63
    int s = row & (S_ - 1), b = row >> 11;
    const float* base = qkv + (size_t)row * F_;
    if (head < NH_ + NKV_) {
        int isK = head >= NH_;
        int hh = isK ? head - NH_ : head;
        int coloff = isK ? NH_ * D_ + hh * D_ : hh * D_;
        float x = base[coloff + d];
        int i = d & 31;
        float pos = (float)positions[s];
        float inv = __expf(-(float)i * (9.210340371976184f / 32.0f));  // 10000^(-i/32)
        float sn, cs;
        sincosf(pos * inv, &sn, &cs);
        float partner = (d < 32) ? base[coloff + d + 32] : base[coloff + d - 32];
        float sign = (d < 32) ? -1.0f : 1.0f;
        float o = x * cs + sign * partner * sn;
        if (!isK)
            Q[((size_t)(b * NH_ + hh) * S_ + s) * D_ + d] = (bf16)(o * QSCALE_);
        else
            Kb[((size_t)(b * NKV_ + hh) * S_ + s) * D_ + d] = (bf16)o;
    } else {
        int hv = head - NH_ - NKV_;
        float v = base[NH_ * D_ + NKV_ * D_ + hv * D_ + d];
        Vt[((size_t)(b * NKV_ + hv) * D_ + d) * S_ + s] = (bf16)v;
    }
}

// ---------------- causal GQA flash attention: 4 q-heads per block share KV via LDS ----------
// Block = 4 waves; wave w handles q-head kvh*4+w. Each 64-key chunk of K and V is
// staged once into LDS in *MFMA-fragment order* by global_load_lds (dest = uniform
// base + lane*16 == exactly the frag-read order, so ds_read is base+lane*16,
// conflict-free). Cuts global K/V traffic 4x vs per-head reads and removes the
// 64-VGPR K/V fragment footprint that caused R3/R4 scratch spill.
// Tile pairing (i, 127-i) balances causal work across blocks.
__global__ __launch_bounds__(256, 4) void flash_attn(const bf16* __restrict__ Q,
                                                     const bf16* __restrict__ Kb,
                                                     const bf16* __restrict__ Vt,
                                                     bf16* __restrict__ ctx) {
    __shared__ __attribute__((aligned(16))) bf16 Ks[8 * 512];   // 8 KB: K frags (hf*4+tl)
    __shared__ __attribute__((aligned(16))) bf16 Vs[8 * 512];   // 8 KB: V frags (hf*4+dt)
    __shared__ __attribute__((aligned(16))) bf16 Plds[4][16 * 72];
    const int tid = threadIdx.x;
    const int w = tid >> 6, lane = tid & 63;
    const int t = lane & 15, quad = lane >> 4;
    const int kvh = blockIdx.y, b = blockIdx.z;
    const int h = kvh * 4 + w;
    const int bh = b * NH_ + h;
    const int bhk = b * NKV_ + kvh;
    const bf16* Kbase = Kb + (size_t)bhk * S_ * D_;
    const bf16* Vbase = Vt + (size_t)bhk * D_ * S_;

    for (int rep = 0; rep < 2; ++rep) {
        const int tileIdx = rep ? (127 - (int)blockIdx.x) : (int)blockIdx.x;
        const int qbase = tileIdx * 16;
        const int kend = qbase + 16;

        const bf16* Qp = Q + ((size_t)bh * S_ + qbase) * D_;
        bf16x8 qf0 = *reinterpret_cast<const bf16x8*>(Qp + t * D_ + quad * 8);
        bf16x8 qf1 = *reinterpret_cast<const bf16x8*>(Qp + t * D_ + 32 + quad * 8);

        f32x4 o[4] = {};
        float m = -1e30f, l = 0.f;

        for (int k0 = 0; k0 < kend; k0 += 64) {
            __syncthreads();  // prev chunk fully consumed before overwrite
            // cooperative staging: wave w stages fragments c = 4w..4w+3 (K: c<8, V: c>=8)
#pragma unroll
            for (int j = 0; j < 4; ++j) {
                const int c = w * 4 + j;
                if (c < 8) {
                    const int tl = c & 3, hf = c >> 2;
                    const bf16* src =
                        Kbase + (size_t)(k0 + tl * 16 + t) * D_ + hf * 32 + quad * 8;
                    __builtin_amdgcn_global_load_lds(GLOBAL_AS(src), LDS_AS(Ks + c * 512), 16, 0,
                                                     0);
                } else {
                    const int cv = c - 8, dt = cv & 3, hf = cv >> 2;
                    const bf16* src =
                        Vbase + (size_t)(dt * 16 + t) * S_ + k0 + hf * 32 + quad * 8;
                    __builtin_amdgcn_global_load_lds(GLOBAL_AS(src), LDS_AS(Vs + cv * 512), 16, 0,
                                                     0);
                }
            }
            __syncthreads();  // drains vmcnt: staged data visible

            f32x4 sa[4] = {};
#pragma unroll
            for (int tl = 0; tl < 4; ++tl) {
                bf16x8 kf0 = *reinterpret_cast<const bf16x8*>(Ks + (tl)*512 + lane * 8);
                bf16x8 kf1 = *reinterpret_cast<const bf16x8*>(Ks + (4 + tl) * 512 + lane * 8);
                sa[tl] = __builtin_amdgcn_mfma_f32_16x16x32_bf16(kf0, qf0, sa[tl], 0, 0, 0);
                sa[tl] = __builtin_amdgcn_mfma_f32_16x16x32_bf16(kf1, qf1, sa[tl], 0, 0, 0);
            }
            // causal mask: only the last chunk touches the diagonal
            if (k0 + 64 >= kend) {
                const int qrow = qbase + t;
#pragma unroll
                for (int tl = 0; tl < 4; ++tl)
#pragma unroll
                    for (int r = 0; r < 4; ++r)
                        if (k0 + tl * 16 + quad * 4 + r > qrow) sa[tl][r] = -1e30f;
            }
            // online softmax over 64 keys; row = q = t (scores are base-2 scaled)
            float mx = -1e30f;
#pragma unroll
            for (int tl = 0; tl < 4; ++tl)
#pragma unroll
                for (int r = 0; r < 4; ++r) mx = fmaxf(mx, sa[tl][r]);
            mx = fmaxf(mx, __shfl_xor(mx, 16, 64));
            mx = fmaxf(mx, __shfl_xor(mx, 32, 64));
            const float mn = fmaxf(m, mx);
            const float alpha = exp2f(m - mn);
            m = mn;
            float rs = 0.f;
#pragma unroll
            for (int tl = 0; tl < 4; ++tl) {
                float p0 = exp2f(sa[tl][0] - mn);
                float p1 = exp2f(sa[tl][1] - mn);
                float p2 = exp2f(sa[tl][2] - mn);
                float p3 = exp2f(sa[tl][3] - mn);
                rs += (p0 + p1) + (p2 + p3);
                bf16x4 pk = {(bf16)p0, (bf16)p1, (bf16)p2, (bf16)p3};
                *reinterpret_cast<bf16x4*>(&Plds[w][t * 72 + tl * 16 + quad * 4]) = pk;
            }
#pragma unroll
            for (int dt = 0; dt < 4; ++dt)
#pragma unroll
                for (int r = 0; r < 4; ++r) o[dt][r] *= alpha;
            rs += __shfl_xor(rs, 16, 64);
            rs += __shfl_xor(rs, 32, 64);
            l = l * alpha + rs;

            asm volatile("s_waitcnt lgkmcnt(0)" ::: "memory");
            bf16x8 pf0 = *reinterpret_cast<const bf16x8*>(&Plds[w][t * 72 + quad * 8]);
            bf16x8 pf1 = *reinterpret_cast<const bf16x8*>(&Plds[w][t * 72 + 32 + quad * 8]);
            asm volatile("" ::: "memory");
#pragma unroll
            for (int dt = 0; dt < 4; ++dt) {
                bf16x8 vf0 = *reinterpret_cast<const bf16x8*>(Vs + (dt)*512 + lane * 8);
                bf16x8 vf1 = *reinterpret_cast<const bf16x8*>(Vs + (4 + dt) * 512 + lane * 8);
                o[dt] = __builtin_amdgcn_mfma_f32_16x16x32_bf16(vf0, pf0, o[dt], 0, 0, 0);
                o[dt] = __builtin_amdgcn_mfma_f32_16x16x32_bf16(vf1, pf1, o[dt], 0, 0, 0);
            }
        }
        // O^T C-layout: lane holds q=t, d=dt*16+quad*4+r -> 8B packed stores
        const float inv = 1.0f / l;
        const size_t row = (size_t)b * S_ + qbase + t;
#pragma unroll
        for (int dt = 0; dt < 4; ++dt) {
            bf16x4 ov = {(bf16)(o[dt][0] * inv), (bf16)(o[dt][1] * inv),
                         (bf16)(o[dt][2] * inv), (bf16)(o[dt][3] * inv)};
            *reinterpret_cast<bf16x4*>(ctx + row * (NH_ * D_) + h * D_ + dt * 16 + quad * 4) = ov;
        }
    }
}

extern "C" void kernel_launch(void* const* d_in, const int* in_sizes, int n_in,
                              void* d_out, int out_size, void* d_ws, size_t ws_size,
                              hipStream_t stream) {
    const int* positions = (const int*)d_in[0];
    const float* hidden = (const float*)d_in[1];
    const float* Wqkv = (const float*)d_in[2];
    const float* Wo = (const float*)d_in[3];
    float* out = (float*)d_out;

    char* ws = (char*)d_ws;
    size_t off = 0;
    auto carve = [&](size_t bytes) {
        void* p = ws + off;
        off += (bytes + 255) & ~(size_t)255;
        return p;
    };
    bf16* hidB = (bf16*)carve((size_t)B_ * S_ * H_ * 2);
    bf16* WqkvT = (bf16*)carve((size_t)F_ * H_ * 2);
    bf16* WoT = (bf16*)carve((size_t)H_ * H_ * 2);
    float* qkv = (float*)carve((size_t)B_ * S_ * F_ * 4);
    bf16* Qb = (bf16*)carve((size_t)B_ * NH_ * S_ * D_ * 2);
    bf16* Kbb = (bf16*)carve((size_t)B_ * NKV_ * S_ * D_ * 2);
    bf16* Vt = (bf16*)carve((size_t)B_ * NKV_ * S_ * D_ * 2);
    bf16* ctx = (bf16*)carve((size_t)B_ * S_ * NH_ * D_ * 2);

    cvt_f32_bf16<<<(B_ * S_ * H_ / 4 + 255) / 256, 256, 0, stream>>>((const float4*)hidden, hidB,
                                                                     B_ * S_ * H_ / 4);
    transpose_to_bf16<<<dim3(F_ / 32, H_ / 32), dim3(32, 8), 0, stream>>>(Wqkv, WqkvT, H_, F_);
    transpose_to_bf16<<<dim3(H_ / 32, H_ / 32), dim3(32, 8), 0, stream>>>(Wo, WoT, H_, H_);
    gemm_bt<<<dim3(F_ / 128, (B_ * S_) / 128), 256, 0, stream>>>(hidB, WqkvT, qkv, B_ * S_, F_, H_);
    rope_split<<<dim3(B_ * S_, NH_ + 2 * NKV_), 64, 0, stream>>>(qkv, positions, Qb, Kbb, Vt);
    flash_attn<<<dim3(64, NKV_, B_), 256, 0, stream>>>(Qb, Kbb, Vt, ctx);
    gemm_bt<<<dim3(H_ / 128, (B_ * S_) / 128), 256, 0, stream>>>(ctx, WoT, out, B_ * S_, H_, H_);
}

// Round 6
// 352.131 us; speedup vs baseline: 3.3023x; 1.1027x over previous
//
#include <hip/hip_runtime.h>
#include <hip/hip_bf16.h>
#include <math.h>

#define B_ 2
#define S_ 2048
#define H_ 2048
#define NH_ 32
#define NKV_ 8
#define D_ 64
#define F_ 3072            // (NH + 2*NKV) * D
#define SCALE_ 0.125f      // 1/sqrt(64)
#define QSCALE_ 0.18033688011112042f   // SCALE_ * log2(e); lets attn use exp2f
#define LN1E4_32_ 0.28782313662425575f // ln(10000)/32

using bf16 = __bf16;
using bf16x4 = __attribute__((ext_vector_type(4))) __bf16;
using bf16x8 = __attribute__((ext_vector_type(8))) __bf16;
using f32x4 = __attribute__((ext_vector_type(4))) float;

#define GLOBAL_AS(p) ((__attribute__((address_space(1))) void*)(p))
#define LDS_AS(p)    ((__attribute__((address_space(3))) void*)(p))

// ---------------- fp32 -> bf16 convert (vectorized) ----------------
__global__ void cvt_f32_bf16(const float4* __restrict__ in, bf16* __restrict__ out, int n4) {
    int i = blockIdx.x * 256 + threadIdx.x;
    if (i >= n4) return;
    float4 v = in[i];
    bf16x4 o = {(bf16)v.x, (bf16)v.y, (bf16)v.z, (bf16)v.w};
    *reinterpret_cast<bf16x4*>(out + (size_t)i * 4) = o;
}

// ---------------- transpose + convert: in fp32 [K][N] -> out bf16 [N][K] ----------------
__global__ void transpose_to_bf16(const float* __restrict__ in, bf16* __restrict__ out,
                                  int K, int N) {
    __shared__ float tile[32][33];
    int n0 = blockIdx.x * 32, k0 = blockIdx.y * 32;
    int tx = threadIdx.x, ty = threadIdx.y;   // (32, 8)
#pragma unroll
    for (int i = 0; i < 4; ++i)
        tile[ty + i * 8][tx] = in[(size_t)(k0 + ty + i * 8) * N + n0 + tx];
    __syncthreads();
#pragma unroll
    for (int i = 0; i < 4; ++i)
        out[(size_t)(n0 + ty + i * 8) * K + k0 + tx] = (bf16)tile[tx][ty + i * 8];
}

// ---------------- fused QKV GEMM + RoPE + head split ----------------
// C = hidden[4096x2048] * WqkvT[3072x2048]^T. Epilogue applies NeoX RoPE and
// writes bf16 directly to Q/[B*NH][S][D] (pre-scaled), K/[B*NKV][S][D],
// Vt/[B*NKV][D][S]. Key fact: in MFMA C-layout, lane t's 4 columns within its
// wave's 64-col (== one head) subtile are d={t,16+t,32+t,48+t}; NeoX partner
// pairs (d,d+32) are (j=0,j=2),(j=1,j=3) -> rotation is in-register, no shuffle.
__global__ __launch_bounds__(256) void gemm_qkv_rope(const bf16* __restrict__ A,
                                                     const bf16* __restrict__ BT,
                                                     const int* __restrict__ positions,
                                                     bf16* __restrict__ Q,
                                                     bf16* __restrict__ Kb,
                                                     bf16* __restrict__ Vt) {
    __shared__ __attribute__((aligned(16))) bf16 As[128 * 32];
    __shared__ __attribute__((aligned(16))) bf16 Bs[128 * 32];
    const int tid = threadIdx.x;
    const int w = tid >> 6, lane = tid & 63;
    const int t = lane & 15, quad = lane >> 4;
    const int m0 = blockIdx.y * 128, n0 = blockIdx.x * 128;
    const int wm = (w >> 1) * 64, wn = (w & 1) * 64;
    const int lrow = lane >> 2;
    const int lcol = (lane & 3) * 8;

    f32x4 acc[4][4] = {};

    for (int k0 = 0; k0 < H_; k0 += 32) {
#pragma unroll
        for (int i = 0; i < 2; ++i) {
            int c = w * 2 + i;
            const bf16* ga = A + (size_t)(m0 + c * 16 + lrow) * H_ + k0 + lcol;
            __builtin_amdgcn_global_load_lds(GLOBAL_AS(ga), LDS_AS(As + c * 512), 16, 0, 0);
            const bf16* gb = BT + (size_t)(n0 + c * 16 + lrow) * H_ + k0 + lcol;
            __builtin_amdgcn_global_load_lds(GLOBAL_AS(gb), LDS_AS(Bs + c * 512), 16, 0, 0);
        }
        __syncthreads();
        bf16x8 a[4], b[4];
#pragma unroll
        for (int i = 0; i < 4; ++i)
            a[i] = *reinterpret_cast<const bf16x8*>(As + (wm + i * 16 + t) * 32 + quad * 8);
#pragma unroll
        for (int j = 0; j < 4; ++j)
            b[j] = *reinterpret_cast<const bf16x8*>(Bs + (wn + j * 16 + t) * 32 + quad * 8);
#pragma unroll
        for (int i = 0; i < 4; ++i)
#pragma unroll
            for (int j = 0; j < 4; ++j)
                acc[i][j] = __builtin_amdgcn_mfma_f32_16x16x32_bf16(a[i], b[j], acc[i][j], 0, 0, 0);
        __syncthreads();
    }

    // ---- epilogue: RoPE + split (wave-uniform head) ----
    const int hseg = (n0 + wn) >> 6;   // 0..47: Q heads 0..31, K 32..39, V 40..47
    if (hseg < NH_ + NKV_) {
        const bool isQ = hseg < NH_;
        const float qs = isQ ? QSCALE_ : 1.0f;
        bf16* dst = isQ ? Q : Kb;
        const int hh = isQ ? hseg : hseg - NH_;
        const int nh = isQ ? NH_ : NKV_;
        const float inv0 = __expf(-(float)t * LN1E4_32_);
        const float inv1 = inv0 * 0.01f;   // 10000^(-16/32) = 1/100 exactly
#pragma unroll
        for (int i = 0; i < 4; ++i)
#pragma unroll
            for (int r = 0; r < 4; ++r) {
                const int mrow = m0 + wm + i * 16 + quad * 4 + r;
                const int s = mrow & (S_ - 1), b = mrow >> 11;
                const float pos = (float)positions[s];
                float sn0, cs0, sn1, cs1;
                sincosf(pos * inv0, &sn0, &cs0);
                sincosf(pos * inv1, &sn1, &cs1);
                const float x0 = acc[i][0][r], x1 = acc[i][1][r];
                const float x2 = acc[i][2][r], x3 = acc[i][3][r];
                bf16 o0 = (bf16)((x0 * cs0 - x2 * sn0) * qs);
                bf16 o1 = (bf16)((x1 * cs1 - x3 * sn1) * qs);
                bf16 o2 = (bf16)((x2 * cs0 + x0 * sn0) * qs);
                bf16 o3 = (bf16)((x3 * cs1 + x1 * sn1) * qs);
                bf16* p = dst + ((size_t)(b * nh + hh) * S_ + s) * D_;
                p[t] = o0;
                p[16 + t] = o1;
                p[32 + t] = o2;
                p[48 + t] = o3;
            }
    } else {
        const int hv = hseg - NH_ - NKV_;
#pragma unroll
        for (int i = 0; i < 4; ++i)
#pragma unroll
            for (int r = 0; r < 4; ++r) {
                const int mrow = m0 + wm + i * 16 + quad * 4 + r;
                const int s = mrow & (S_ - 1), b = mrow >> 11;
                bf16* p = Vt + ((size_t)(b * NKV_ + hv) * D_) * S_ + s;
#pragma unroll
                for (int j = 0; j < 4; ++j)
                    p[(size_t)(j * 16 + t) * S_] = (bf16)acc[i][j][r];
            }
    }
}

// ---------------- bf16 MFMA GEMM: C[M][N] = A[M][K] * BT[N][K]^T, fp32 out ----------------
__global__ __launch_bounds__(256) void gemm_bt(const bf16* __restrict__ A,
                                               const bf16* __restrict__ BT,
                                               float* __restrict__ C,
                                               int M, int N, int K) {
    __shared__ __attribute__((aligned(16))) bf16 As[128 * 32];
    __shared__ __attribute__((aligned(16))) bf16 Bs[128 * 32];
    const int tid = threadIdx.x;
    const int w = tid >> 6, lane = tid & 63;
    const int t = lane & 15, quad = lane >> 4;
    const int m0 = blockIdx.y * 128, n0 = blockIdx.x * 128;
    const int wm = (w >> 1) * 64, wn = (w & 1) * 64;
    const int lrow = lane >> 2;
    const int lcol = (lane & 3) * 8;

    f32x4 acc[4][4] = {};

    for (int k0 = 0; k0 < K; k0 += 32) {
#pragma unroll
        for (int i = 0; i < 2; ++i) {
            int c = w * 2 + i;
            const bf16* ga = A + (size_t)(m0 + c * 16 + lrow) * K + k0 + lcol;
            __builtin_amdgcn_global_load_lds(GLOBAL_AS(ga), LDS_AS(As + c * 512), 16, 0, 0);
            const bf16* gb = BT + (size_t)(n0 + c * 16 + lrow) * K + k0 + lcol;
            __builtin_amdgcn_global_load_lds(GLOBAL_AS(gb), LDS_AS(Bs + c * 512), 16, 0, 0);
        }
        __syncthreads();
        bf16x8 a[4], b[4];
#pragma unroll
        for (int i = 0; i < 4; ++i)
            a[i] = *reinterpret_cast<const bf16x8*>(As + (wm + i * 16 + t) * 32 + quad * 8);
#pragma unroll
        for (int j = 0; j < 4; ++j)
            b[j] = *reinterpret_cast<const bf16x8*>(Bs + (wn + j * 16 + t) * 32 + quad * 8);
#pragma unroll
        for (int i = 0; i < 4; ++i)
#pragma unroll
            for (int j = 0; j < 4; ++j)
                acc[i][j] = __builtin_amdgcn_mfma_f32_16x16x32_bf16(a[i], b[j], acc[i][j], 0, 0, 0);
        __syncthreads();
    }
#pragma unroll
    for (int i = 0; i < 4; ++i)
#pragma unroll
        for (int j = 0; j < 4; ++j)
#pragma unroll
            for (int r = 0; r < 4; ++r)
                C[(size_t)(m0 + wm + i * 16 + quad * 4 + r) * N + n0 + wn + j * 16 + t] =
                    acc[i][j][r];
}

// ---------------- causal GQA flash attention: 4 q-heads per block share KV via LDS ----------
// Block = 4 waves; wave w handles q-head kvh*4+w. Each 64-key chunk of K and V is
// staged once into LDS in *MFMA-fragment order* by global_load_lds (dest = uniform
// base + lane*16 == exactly the frag-read order, so ds_read is base+lane*16,
// conflict-free). Tile pairing (i, 127-i) balances causal work across blocks.
__global__ __launch_bounds__(256, 4) void flash_attn(const bf16* __restrict__ Q,
                                                     const bf16* __restrict__ Kb,
                                                     const bf16* __restrict__ Vt,
                                                     bf16* __restrict__ ctx) {
    __shared__ __attribute__((aligned(16))) bf16 Ks[8 * 512];   // 8 KB: K frags (hf*4+tl)
    __shared__ __attribute__((aligned(16))) bf16 Vs[8 * 512];   // 8 KB: V frags (hf*4+dt)
    __shared__ __attribute__((aligned(16))) bf16 Plds[4][16 * 72];
    const int tid = threadIdx.x;
    const int w = tid >> 6, lane = tid & 63;
    const int t = lane & 15, quad = lane >> 4;
    const int kvh = blockIdx.y, b = blockIdx.z;
    const int h = kvh * 4 + w;
    const int bh = b * NH_ + h;
    const int bhk = b * NKV_ + kvh;
    const bf16* Kbase = Kb + (size_t)bhk * S_ * D_;
    const bf16* Vbase = Vt + (size_t)bhk * D_ * S_;

    for (int rep = 0; rep < 2; ++rep) {
        const int tileIdx = rep ? (127 - (int)blockIdx.x) : (int)blockIdx.x;
        const int qbase = tileIdx * 16;
        const int kend = qbase + 16;

        const bf16* Qp = Q + ((size_t)bh * S_ + qbase) * D_;
        bf16x8 qf0 = *reinterpret_cast<const bf16x8*>(Qp + t * D_ + quad * 8);
        bf16x8 qf1 = *reinterpret_cast<const bf16x8*>(Qp + t * D_ + 32 + quad * 8);

        f32x4 o[4] = {};
        float m = -1e30f, l = 0.f;

        for (int k0 = 0; k0 < kend; k0 += 64) {
            __syncthreads();  // prev chunk fully consumed before overwrite
            // cooperative staging: wave w stages fragments c = 4w..4w+3 (K: c<8, V: c>=8)
#pragma unroll
            for (int j = 0; j < 4; ++j) {
                const int c = w * 4 + j;
                if (c < 8) {
                    const int tl = c & 3, hf = c >> 2;
                    const bf16* src =
                        Kbase + (size_t)(k0 + tl * 16 + t) * D_ + hf * 32 + quad * 8;
                    __builtin_amdgcn_global_load_lds(GLOBAL_AS(src), LDS_AS(Ks + c * 512), 16, 0,
                                                     0);
                } else {
                    const int cv = c - 8, dt = cv & 3, hf = cv >> 2;
                    const bf16* src =
                        Vbase + (size_t)(dt * 16 + t) * S_ + k0 + hf * 32 + quad * 8;
                    __builtin_amdgcn_global_load_lds(GLOBAL_AS(src), LDS_AS(Vs + cv * 512), 16, 0,
                                                     0);
                }
            }
            __syncthreads();  // drains vmcnt: staged data visible

            f32x4 sa[4] = {};
#pragma unroll
            for (int tl = 0; tl < 4; ++tl) {
                bf16x8 kf0 = *reinterpret_cast<const bf16x8*>(Ks + (tl)*512 + lane * 8);
                bf16x8 kf1 = *reinterpret_cast<const bf16x8*>(Ks + (4 + tl) * 512 + lane * 8);
                sa[tl] = __builtin_amdgcn_mfma_f32_16x16x32_bf16(kf0, qf0, sa[tl], 0, 0, 0);
                sa[tl] = __builtin_amdgcn_mfma_f32_16x16x32_bf16(kf1, qf1, sa[tl], 0, 0, 0);
            }
            // causal mask: only the last chunk touches the diagonal
            if (k0 + 64 >= kend) {
                const int qrow = qbase + t;
#pragma unroll
                for (int tl = 0; tl < 4; ++tl)
#pragma unroll
                    for (int r = 0; r < 4; ++r)
                        if (k0 + tl * 16 + quad * 4 + r > qrow) sa[tl][r] = -1e30f;
            }
            // online softmax over 64 keys; row = q = t (scores are base-2 scaled)
            float mx = -1e30f;
#pragma unroll
            for (int tl = 0; tl < 4; ++tl)
#pragma unroll
                for (int r = 0; r < 4; ++r) mx = fmaxf(mx, sa[tl][r]);
            mx = fmaxf(mx, __shfl_xor(mx, 16, 64));
            mx = fmaxf(mx, __shfl_xor(mx, 32, 64));
            const float mn = fmaxf(m, mx);
            const float alpha = exp2f(m - mn);
            m = mn;
            float rs = 0.f;
#pragma unroll
            for (int tl = 0; tl < 4; ++tl) {
                float p0 = exp2f(sa[tl][0] - mn);
                float p1 = exp2f(sa[tl][1] - mn);
                float p2 = exp2f(sa[tl][2] - mn);
                float p3 = exp2f(sa[tl][3] - mn);
                rs += (p0 + p1) + (p2 + p3);
                bf16x4 pk = {(bf16)p0, (bf16)p1, (bf16)p2, (bf16)p3};
                *reinterpret_cast<bf16x4*>(&Plds[w][t * 72 + tl * 16 + quad * 4]) = pk;
            }
#pragma unroll
            for (int dt = 0; dt < 4; ++dt)
#pragma unroll
                for (int r = 0; r < 4; ++r) o[dt][r] *= alpha;
            rs += __shfl_xor(rs, 16, 64);
            rs += __shfl_xor(rs, 32, 64);
            l = l * alpha + rs;

            asm volatile("s_waitcnt lgkmcnt(0)" ::: "memory");
            bf16x8 pf0 = *reinterpret_cast<const bf16x8*>(&Plds[w][t * 72 + quad * 8]);
            bf16x8 pf1 = *reinterpret_cast<const bf16x8*>(&Plds[w][t * 72 + 32 + quad * 8]);
            asm volatile("" ::: "memory");
#pragma unroll
            for (int dt = 0; dt < 4; ++dt) {
                bf16x8 vf0 = *reinterpret_cast<const bf16x8*>(Vs + (dt)*512 + lane * 8);
                bf16x8 vf1 = *reinterpret_cast<const bf16x8*>(Vs + (4 + dt) * 512 + lane * 8);
                o[dt] = __builtin_amdgcn_mfma_f32_16x16x32_bf16(vf0, pf0, o[dt], 0, 0, 0);
                o[dt] = __builtin_amdgcn_mfma_f32_16x16x32_bf16(vf1, pf1, o[dt], 0, 0, 0);
            }
        }
        // O^T C-layout: lane holds q=t, d=dt*16+quad*4+r -> 8B packed stores
        const float inv = 1.0f / l;
        const size_t row = (size_t)b * S_ + qbase + t;
#pragma unroll
        for (int dt = 0; dt < 4; ++dt) {
            bf16x4 ov = {(bf16)(o[dt][0] * inv), (bf16)(o[dt][1] * inv),
                         (bf16)(o[dt][2] * inv), (bf16)(o[dt][3] * inv)};
            *reinterpret_cast<bf16x4*>(ctx + row * (NH_ * D_) + h * D_ + dt * 16 + quad * 4) = ov;
        }
    }
}

extern "C" void kernel_launch(void* const* d_in, const int* in_sizes, int n_in,
                              void* d_out, int out_size, void* d_ws, size_t ws_size,
                              hipStream_t stream) {
    const int* positions = (const int*)d_in[0];
    const float* hidden = (const float*)d_in[1];
    const float* Wqkv = (const float*)d_in[2];
    const float* Wo = (const float*)d_in[3];
    float* out = (float*)d_out;

    char* ws = (char*)d_ws;
    size_t off = 0;
    auto carve = [&](size_t bytes) {
        void* p = ws + off;
        off += (bytes + 255) & ~(size_t)255;
        return p;
    };
    bf16* hidB = (bf16*)carve((size_t)B_ * S_ * H_ * 2);
    bf16* WqkvT = (bf16*)carve((size_t)F_ * H_ * 2);
    bf16* WoT = (bf16*)carve((size_t)H_ * H_ * 2);
    bf16* Qb = (bf16*)carve((size_t)B_ * NH_ * S_ * D_ * 2);
    bf16* Kbb = (bf16*)carve((size_t)B_ * NKV_ * S_ * D_ * 2);
    bf16* Vt = (bf16*)carve((size_t)B_ * NKV_ * S_ * D_ * 2);
    bf16* ctx = (bf16*)carve((size_t)B_ * S_ * NH_ * D_ * 2);

    cvt_f32_bf16<<<(B_ * S_ * H_ / 4 + 255) / 256, 256, 0, stream>>>((const float4*)hidden, hidB,
                                                                     B_ * S_ * H_ / 4);
    transpose_to_bf16<<<dim3(F_ / 32, H_ / 32), dim3(32, 8), 0, stream>>>(Wqkv, WqkvT, H_, F_);
    transpose_to_bf16<<<dim3(H_ / 32, H_ / 32), dim3(32, 8), 0, stream>>>(Wo, WoT, H_, H_);
    gemm_qkv_rope<<<dim3(F_ / 128, (B_ * S_) / 128), 256, 0, stream>>>(hidB, WqkvT, positions, Qb,
                                                                       Kbb, Vt);
    flash_attn<<<dim3(64, NKV_, B_), 256, 0, stream>>>(Qb, Kbb, Vt, ctx);
    gemm_bt<<<dim3(H_ / 128, (B_ * S_) / 128), 256, 0, stream>>>(ctx, WoT, out, B_ * S_, H_, H_);
}

// Round 7
// 335.726 us; speedup vs baseline: 3.4636x; 1.0489x over previous
//
#include <hip/hip_runtime.h>
#include <hip/hip_bf16.h>
#include <math.h>

#define B_ 2
#define S_ 2048
#define H_ 2048
#define NH_ 32
#define NKV_ 8
#define D_ 64
#define F_ 3072            // (NH + 2*NKV) * D
#define SCALE_ 0.125f      // 1/sqrt(64)
#define QSCALE_ 0.18033688011112042f   // SCALE_ * log2(e); lets attn use exp2f
#define LN1E4_32_ 0.28782313662425575f // ln(10000)/32

using bf16 = __bf16;
using bf16x4 = __attribute__((ext_vector_type(4))) __bf16;
using bf16x8 = __attribute__((ext_vector_type(8))) __bf16;
using f32x4 = __attribute__((ext_vector_type(4))) float;

#define GLOBAL_AS(p) ((__attribute__((address_space(1))) void*)(p))
#define LDS_AS(p)    ((__attribute__((address_space(3))) void*)(p))

// ---------------- fp32 -> bf16 convert (vectorized) ----------------
__global__ void cvt_f32_bf16(const float4* __restrict__ in, bf16* __restrict__ out, int n4) {
    int i = blockIdx.x * 256 + threadIdx.x;
    if (i >= n4) return;
    float4 v = in[i];
    bf16x4 o = {(bf16)v.x, (bf16)v.y, (bf16)v.z, (bf16)v.w};
    *reinterpret_cast<bf16x4*>(out + (size_t)i * 4) = o;
}

// ---------------- transpose + convert: in fp32 [K][N] -> out bf16 [N][K] ----------------
__global__ void transpose_to_bf16(const float* __restrict__ in, bf16* __restrict__ out,
                                  int K, int N) {
    __shared__ float tile[32][33];
    int n0 = blockIdx.x * 32, k0 = blockIdx.y * 32;
    int tx = threadIdx.x, ty = threadIdx.y;   // (32, 8)
#pragma unroll
    for (int i = 0; i < 4; ++i)
        tile[ty + i * 8][tx] = in[(size_t)(k0 + ty + i * 8) * N + n0 + tx];
    __syncthreads();
#pragma unroll
    for (int i = 0; i < 4; ++i)
        out[(size_t)(n0 + ty + i * 8) * K + k0 + tx] = (bf16)tile[tx][ty + i * 8];
}

// ---------------- fused QKV GEMM + RoPE + head split ----------------
__global__ __launch_bounds__(256) void gemm_qkv_rope(const bf16* __restrict__ A,
                                                     const bf16* __restrict__ BT,
                                                     const int* __restrict__ positions,
                                                     bf16* __restrict__ Q,
                                                     bf16* __restrict__ Kb,
                                                     bf16* __restrict__ Vt) {
    __shared__ __attribute__((aligned(16))) bf16 As[128 * 32];
    __shared__ __attribute__((aligned(16))) bf16 Bs[128 * 32];
    const int tid = threadIdx.x;
    const int w = tid >> 6, lane = tid & 63;
    const int t = lane & 15, quad = lane >> 4;
    const int m0 = blockIdx.y * 128, n0 = blockIdx.x * 128;
    const int wm = (w >> 1) * 64, wn = (w & 1) * 64;
    const int lrow = lane >> 2;
    const int lcol = (lane & 3) * 8;

    f32x4 acc[4][4] = {};

    for (int k0 = 0; k0 < H_; k0 += 32) {
#pragma unroll
        for (int i = 0; i < 2; ++i) {
            int c = w * 2 + i;
            const bf16* ga = A + (size_t)(m0 + c * 16 + lrow) * H_ + k0 + lcol;
            __builtin_amdgcn_global_load_lds(GLOBAL_AS(ga), LDS_AS(As + c * 512), 16, 0, 0);
            const bf16* gb = BT + (size_t)(n0 + c * 16 + lrow) * H_ + k0 + lcol;
            __builtin_amdgcn_global_load_lds(GLOBAL_AS(gb), LDS_AS(Bs + c * 512), 16, 0, 0);
        }
        __syncthreads();
        bf16x8 a[4], b[4];
#pragma unroll
        for (int i = 0; i < 4; ++i)
            a[i] = *reinterpret_cast<const bf16x8*>(As + (wm + i * 16 + t) * 32 + quad * 8);
#pragma unroll
        for (int j = 0; j < 4; ++j)
            b[j] = *reinterpret_cast<const bf16x8*>(Bs + (wn + j * 16 + t) * 32 + quad * 8);
#pragma unroll
        for (int i = 0; i < 4; ++i)
#pragma unroll
            for (int j = 0; j < 4; ++j)
                acc[i][j] = __builtin_amdgcn_mfma_f32_16x16x32_bf16(a[i], b[j], acc[i][j], 0, 0, 0);
        __syncthreads();
    }

    // ---- epilogue: RoPE + split (wave-uniform head) ----
    const int hseg = (n0 + wn) >> 6;   // 0..47: Q heads 0..31, K 32..39, V 40..47
    if (hseg < NH_ + NKV_) {
        const bool isQ = hseg < NH_;
        const float qs = isQ ? QSCALE_ : 1.0f;
        bf16* dst = isQ ? Q : Kb;
        const int hh = isQ ? hseg : hseg - NH_;
        const int nh = isQ ? NH_ : NKV_;
        const float inv0 = __expf(-(float)t * LN1E4_32_);
        const float inv1 = inv0 * 0.01f;   // 10000^(-16/32) = 1/100 exactly
#pragma unroll
        for (int i = 0; i < 4; ++i)
#pragma unroll
            for (int r = 0; r < 4; ++r) {
                const int mrow = m0 + wm + i * 16 + quad * 4 + r;
                const int s = mrow & (S_ - 1), b = mrow >> 11;
                const float pos = (float)positions[s];
                float sn0, cs0, sn1, cs1;
                sincosf(pos * inv0, &sn0, &cs0);
                sincosf(pos * inv1, &sn1, &cs1);
                const float x0 = acc[i][0][r], x1 = acc[i][1][r];
                const float x2 = acc[i][2][r], x3 = acc[i][3][r];
                bf16 o0 = (bf16)((x0 * cs0 - x2 * sn0) * qs);
                bf16 o1 = (bf16)((x1 * cs1 - x3 * sn1) * qs);
                bf16 o2 = (bf16)((x2 * cs0 + x0 * sn0) * qs);
                bf16 o3 = (bf16)((x3 * cs1 + x1 * sn1) * qs);
                bf16* p = dst + ((size_t)(b * nh + hh) * S_ + s) * D_;
                p[t] = o0;
                p[16 + t] = o1;
                p[32 + t] = o2;
                p[48 + t] = o3;
            }
    } else {
        const int hv = hseg - NH_ - NKV_;
#pragma unroll
        for (int i = 0; i < 4; ++i)
#pragma unroll
            for (int r = 0; r < 4; ++r) {
                const int mrow = m0 + wm + i * 16 + quad * 4 + r;
                const int s = mrow & (S_ - 1), b = mrow >> 11;
                bf16* p = Vt + ((size_t)(b * NKV_ + hv) * D_) * S_ + s;
#pragma unroll
                for (int j = 0; j < 4; ++j)
                    p[(size_t)(j * 16 + t) * S_] = (bf16)acc[i][j][r];
            }
    }
}

// ---------------- bf16 MFMA GEMM: C[M][N] = A[M][K] * BT[N][K]^T, fp32 out ----------------
__global__ __launch_bounds__(256) void gemm_bt(const bf16* __restrict__ A,
                                               const bf16* __restrict__ BT,
                                               float* __restrict__ C,
                                               int M, int N, int K) {
    __shared__ __attribute__((aligned(16))) bf16 As[128 * 32];
    __shared__ __attribute__((aligned(16))) bf16 Bs[128 * 32];
    const int tid = threadIdx.x;
    const int w = tid >> 6, lane = tid & 63;
    const int t = lane & 15, quad = lane >> 4;
    const int m0 = blockIdx.y * 128, n0 = blockIdx.x * 128;
    const int wm = (w >> 1) * 64, wn = (w & 1) * 64;
    const int lrow = lane >> 2;
    const int lcol = (lane & 3) * 8;

    f32x4 acc[4][4] = {};

    for (int k0 = 0; k0 < K; k0 += 32) {
#pragma unroll
        for (int i = 0; i < 2; ++i) {
            int c = w * 2 + i;
            const bf16* ga = A + (size_t)(m0 + c * 16 + lrow) * K + k0 + lcol;
            __builtin_amdgcn_global_load_lds(GLOBAL_AS(ga), LDS_AS(As + c * 512), 16, 0, 0);
            const bf16* gb = BT + (size_t)(n0 + c * 16 + lrow) * K + k0 + lcol;
            __builtin_amdgcn_global_load_lds(GLOBAL_AS(gb), LDS_AS(Bs + c * 512), 16, 0, 0);
        }
        __syncthreads();
        bf16x8 a[4], b[4];
#pragma unroll
        for (int i = 0; i < 4; ++i)
            a[i] = *reinterpret_cast<const bf16x8*>(As + (wm + i * 16 + t) * 32 + quad * 8);
#pragma unroll
        for (int j = 0; j < 4; ++j)
            b[j] = *reinterpret_cast<const bf16x8*>(Bs + (wn + j * 16 + t) * 32 + quad * 8);
#pragma unroll
        for (int i = 0; i < 4; ++i)
#pragma unroll
            for (int j = 0; j < 4; ++j)
                acc[i][j] = __builtin_amdgcn_mfma_f32_16x16x32_bf16(a[i], b[j], acc[i][j], 0, 0, 0);
        __syncthreads();
    }
#pragma unroll
    for (int i = 0; i < 4; ++i)
#pragma unroll
        for (int j = 0; j < 4; ++j)
#pragma unroll
            for (int r = 0; r < 4; ++r)
                C[(size_t)(m0 + wm + i * 16 + quad * 4 + r) * N + n0 + wn + j * 16 + t] =
                    acc[i][j][r];
}

// ---------------- causal GQA flash attention v3 ----------------
// Block = 4 waves = 4 q-heads sharing one KV head via LDS. Two changes vs R5/R6:
// (1) Double-buffered K/V staging: prefetch chunk c+1 into buffer p^1 right after
//     the barrier, compute on p — the barrier's vmcnt drain waits for loads issued
//     a full compute-phase ago (~free). This is the separable-staging pipeline the
//     GEMM structure can't express.
// (2) Merged tile-pair sweep: tiles (i, 127-i) share one K-sweep (tile i's chunks
//     are a prefix of tile 127-i's) -> 25% fewer staged chunks + barriers; compute
//     per block stays constant (129 16-key units).
// Plds: stride 64 + 16B-block XOR swizzle (t&7) keeps LDS at exactly 40960 B
// -> 4 blocks/CU.
__global__ __launch_bounds__(256, 4) void flash_attn(const bf16* __restrict__ Q,
                                                     const bf16* __restrict__ Kb,
                                                     const bf16* __restrict__ Vt,
                                                     bf16* __restrict__ ctx) {
    __shared__ __attribute__((aligned(16))) bf16 Ks[2][8 * 512];
    __shared__ __attribute__((aligned(16))) bf16 Vs[2][8 * 512];
    __shared__ __attribute__((aligned(16))) bf16 Plds[4][16 * 64];
    const int tid = threadIdx.x;
    const int w = tid >> 6, lane = tid & 63;
    const int t = lane & 15, quad = lane >> 4;
    const int sw = t & 7;
    const int kvh = blockIdx.y, b = blockIdx.z;
    const int h = kvh * 4 + w;
    const int bh = b * NH_ + h;
    const int bhk = b * NKV_ + kvh;
    const bf16* Kbase = Kb + (size_t)bhk * S_ * D_;
    const bf16* Vbase = Vt + (size_t)bhk * D_ * S_;

    const int i = blockIdx.x;
    const int qb0 = i * 16, qb1 = (127 - i) * 16;
    const int kend0 = qb0 + 16, kend1 = qb1 + 16;

    const bf16* Qp0 = Q + ((size_t)bh * S_ + qb0) * D_;
    const bf16* Qp1 = Q + ((size_t)bh * S_ + qb1) * D_;
    bf16x8 q0f0 = *reinterpret_cast<const bf16x8*>(Qp0 + t * D_ + quad * 8);
    bf16x8 q0f1 = *reinterpret_cast<const bf16x8*>(Qp0 + t * D_ + 32 + quad * 8);
    bf16x8 q1f0 = *reinterpret_cast<const bf16x8*>(Qp1 + t * D_ + quad * 8);
    bf16x8 q1f1 = *reinterpret_cast<const bf16x8*>(Qp1 + t * D_ + 32 + quad * 8);

    f32x4 o0[4] = {}, o1[4] = {};
    float m0v = -1e30f, l0v = 0.f, m1v = -1e30f, l1v = 0.f;

    auto stage = [&](int k0, int p) {
#pragma unroll
        for (int j = 0; j < 4; ++j) {
            const int c = w * 4 + j;
            if (c < 8) {
                const int tl = c & 3, hf = c >> 2;
                const bf16* src = Kbase + (size_t)(k0 + tl * 16 + t) * D_ + hf * 32 + quad * 8;
                __builtin_amdgcn_global_load_lds(GLOBAL_AS(src), LDS_AS(&Ks[p][c * 512]), 16, 0,
                                                 0);
            } else {
                const int cv = c - 8, dt = cv & 3, hf = cv >> 2;
                const bf16* src = Vbase + (size_t)(dt * 16 + t) * S_ + k0 + hf * 32 + quad * 8;
                __builtin_amdgcn_global_load_lds(GLOBAL_AS(src), LDS_AS(&Vs[p][cv * 512]), 16, 0,
                                                 0);
            }
        }
    };

    auto process = [&](const bf16* ks, const bf16* vs, bf16x8 qf0, bf16x8 qf1, float& m, float& l,
                       f32x4* o, int k0, int qbase, bool domask) {
        f32x4 sa[4] = {};
#pragma unroll
        for (int tl = 0; tl < 4; ++tl) {
            bf16x8 kf0 = *reinterpret_cast<const bf16x8*>(ks + tl * 512 + lane * 8);
            bf16x8 kf1 = *reinterpret_cast<const bf16x8*>(ks + (4 + tl) * 512 + lane * 8);
            sa[tl] = __builtin_amdgcn_mfma_f32_16x16x32_bf16(kf0, qf0, sa[tl], 0, 0, 0);
            sa[tl] = __builtin_amdgcn_mfma_f32_16x16x32_bf16(kf1, qf1, sa[tl], 0, 0, 0);
        }
        if (domask) {
            const int qrow = qbase + t;
#pragma unroll
            for (int tl = 0; tl < 4; ++tl)
#pragma unroll
                for (int r = 0; r < 4; ++r)
                    if (k0 + tl * 16 + quad * 4 + r > qrow) sa[tl][r] = -1e30f;
        }
        float mx = -1e30f;
#pragma unroll
        for (int tl = 0; tl < 4; ++tl)
#pragma unroll
            for (int r = 0; r < 4; ++r) mx = fmaxf(mx, sa[tl][r]);
        mx = fmaxf(mx, __shfl_xor(mx, 16, 64));
        mx = fmaxf(mx, __shfl_xor(mx, 32, 64));
        const float mn = fmaxf(m, mx);
        const float alpha = exp2f(m - mn);
        m = mn;
        float rs = 0.f;
#pragma unroll
        for (int tl = 0; tl < 4; ++tl) {
            float p0 = exp2f(sa[tl][0] - mn);
            float p1 = exp2f(sa[tl][1] - mn);
            float p2 = exp2f(sa[tl][2] - mn);
            float p3 = exp2f(sa[tl][3] - mn);
            rs += (p0 + p1) + (p2 + p3);
            bf16x4 pk = {(bf16)p0, (bf16)p1, (bf16)p2, (bf16)p3};
            // swizzled store: key block8 = tl*2 + (quad>>1), in-block off = (quad&1)*4
            *reinterpret_cast<bf16x4*>(
                &Plds[w][t * 64 + (((tl * 2 + (quad >> 1)) ^ sw) << 3) + (quad & 1) * 4]) = pk;
        }
#pragma unroll
        for (int dt = 0; dt < 4; ++dt)
#pragma unroll
            for (int r = 0; r < 4; ++r) o[dt][r] *= alpha;
        rs += __shfl_xor(rs, 16, 64);
        rs += __shfl_xor(rs, 32, 64);
        l = l * alpha + rs;

        asm volatile("s_waitcnt lgkmcnt(0)" ::: "memory");
        bf16x8 pf0 = *reinterpret_cast<const bf16x8*>(&Plds[w][t * 64 + ((quad ^ sw) << 3)]);
        bf16x8 pf1 =
            *reinterpret_cast<const bf16x8*>(&Plds[w][t * 64 + (((4 + quad) ^ sw) << 3)]);
        asm volatile("" ::: "memory");
#pragma unroll
        for (int dt = 0; dt < 4; ++dt) {
            bf16x8 vf0 = *reinterpret_cast<const bf16x8*>(vs + dt * 512 + lane * 8);
            bf16x8 vf1 = *reinterpret_cast<const bf16x8*>(vs + (4 + dt) * 512 + lane * 8);
            o[dt] = __builtin_amdgcn_mfma_f32_16x16x32_bf16(vf0, pf0, o[dt], 0, 0, 0);
            o[dt] = __builtin_amdgcn_mfma_f32_16x16x32_bf16(vf1, pf1, o[dt], 0, 0, 0);
        }
    };

    const int nch = (kend1 + 63) >> 6;
    stage(0, 0);
    for (int c = 0; c < nch; ++c) {
        const int k0 = c << 6;
        const int p = c & 1;
        __syncthreads();  // drains each wave's vmcnt: buffer p ready; all waves done with p^1
        if (c + 1 < nch) stage((c + 1) << 6, p ^ 1);
        process(&Ks[p][0], &Vs[p][0], q1f0, q1f1, m1v, l1v, o1, k0, qb1, k0 + 64 >= kend1);
        if (k0 < kend0)
            process(&Ks[p][0], &Vs[p][0], q0f0, q0f1, m0v, l0v, o0, k0, qb0, k0 + 64 >= kend0);
    }

    // O^T C-layout epilogue for both tiles: lane holds q=t, d=dt*16+quad*4+r
    {
        const float inv = 1.0f / l0v;
        const size_t row = (size_t)b * S_ + qb0 + t;
#pragma unroll
        for (int dt = 0; dt < 4; ++dt) {
            bf16x4 ov = {(bf16)(o0[dt][0] * inv), (bf16)(o0[dt][1] * inv),
                         (bf16)(o0[dt][2] * inv), (bf16)(o0[dt][3] * inv)};
            *reinterpret_cast<bf16x4*>(ctx + row * (NH_ * D_) + h * D_ + dt * 16 + quad * 4) = ov;
        }
    }
    {
        const float inv = 1.0f / l1v;
        const size_t row = (size_t)b * S_ + qb1 + t;
#pragma unroll
        for (int dt = 0; dt < 4; ++dt) {
            bf16x4 ov = {(bf16)(o1[dt][0] * inv), (bf16)(o1[dt][1] * inv),
                         (bf16)(o1[dt][2] * inv), (bf16)(o1[dt][3] * inv)};
            *reinterpret_cast<bf16x4*>(ctx + row * (NH_ * D_) + h * D_ + dt * 16 + quad * 4) = ov;
        }
    }
}

extern "C" void kernel_launch(void* const* d_in, const int* in_sizes, int n_in,
                              void* d_out, int out_size, void* d_ws, size_t ws_size,
                              hipStream_t stream) {
    const int* positions = (const int*)d_in[0];
    const float* hidden = (const float*)d_in[1];
    const float* Wqkv = (const float*)d_in[2];
    const float* Wo = (const float*)d_in[3];
    float* out = (float*)d_out;

    char* ws = (char*)d_ws;
    size_t off = 0;
    auto carve = [&](size_t bytes) {
        void* p = ws + off;
        off += (bytes + 255) & ~(size_t)255;
        return p;
    };
    bf16* hidB = (bf16*)carve((size_t)B_ * S_ * H_ * 2);
    bf16* WqkvT = (bf16*)carve((size_t)F_ * H_ * 2);
    bf16* WoT = (bf16*)carve((size_t)H_ * H_ * 2);
    bf16* Qb = (bf16*)carve((size_t)B_ * NH_ * S_ * D_ * 2);
    bf16* Kbb = (bf16*)carve((size_t)B_ * NKV_ * S_ * D_ * 2);
    bf16* Vt = (bf16*)carve((size_t)B_ * NKV_ * S_ * D_ * 2);
    bf16* ctx = (bf16*)carve((size_t)B_ * S_ * NH_ * D_ * 2);

    cvt_f32_bf16<<<(B_ * S_ * H_ / 4 + 255) / 256, 256, 0, stream>>>((const float4*)hidden, hidB,
                                                                     B_ * S_ * H_ / 4);
    transpose_to_bf16<<<dim3(F_ / 32, H_ / 32), dim3(32, 8), 0, stream>>>(Wqkv, WqkvT, H_, F_);
    transpose_to_bf16<<<dim3(H_ / 32, H_ / 32), dim3(32, 8), 0, stream>>>(Wo, WoT, H_, H_);
    gemm_qkv_rope<<<dim3(F_ / 128, (B_ * S_) / 128), 256, 0, stream>>>(hidB, WqkvT, positions, Qb,
                                                                       Kbb, Vt);
    flash_attn<<<dim3(64, NKV_, B_), 256, 0, stream>>>(Qb, Kbb, Vt, ctx);
    gemm_bt<<<dim3(H_ / 128, (B_ * S_) / 128), 256, 0, stream>>>(ctx, WoT, out, B_ * S_, H_, H_);
}